// Round 6
// baseline (756.130 us; speedup 1.0000x reference)
//
#include <hip/hip_runtime.h>
#include <hip/hip_bf16.h>
#include <cstddef>

// Problem constants
constexpr int B_  = 2;
constexpr int T_  = 8;
constexpr int HW_ = 37;          // H == W == 37
constexpr int N_  = HW_ * HW_;   // 1369
constexpr int C_  = 384;
constexpr int NH_ = 8;
constexpr int MP_ = 8;
constexpr int HD_ = C_ / NH_;    // 48
constexpr int M_  = B_ * T_ * N_; // 21904

typedef short bf16x8 __attribute__((ext_vector_type(8)));
typedef float f32x4 __attribute__((ext_vector_type(4)));
typedef float f32x2 __attribute__((ext_vector_type(2)));

static __device__ __forceinline__ unsigned short bf16_bits(float v) {
  __hip_bfloat16 b = __float2bfloat16(v);
  return *reinterpret_cast<unsigned short*>(&b);
}

static __device__ __forceinline__ f32x2 unpk(unsigned u) {
  f32x2 r;
  r.x = __uint_as_float(u << 16);
  r.y = __uint_as_float(u & 0xffff0000u);
  return r;
}

// cross-lane adds: xor1/xor2 via DPP quad_perm (VALU pipe), xor4/8/16 via
// ds_swizzle BitMode, xor32 via __shfl_xor (bpermute).
static __device__ __forceinline__ float dpp_add1(float v) {
  int t = __builtin_amdgcn_update_dpp(0, __float_as_int(v), 0xB1, 0xF, 0xF, true);
  return v + __int_as_float(t);
}
static __device__ __forceinline__ float dpp_add2(float v) {
  int t = __builtin_amdgcn_update_dpp(0, __float_as_int(v), 0x4E, 0xF, 0xF, true);
  return v + __int_as_float(t);
}
#define SWZ_XOR4(v)  __int_as_float(__builtin_amdgcn_ds_swizzle(__float_as_int(v), 0x101F))
#define SWZ_XOR8(v)  __int_as_float(__builtin_amdgcn_ds_swizzle(__float_as_int(v), 0x201F))
#define SWZ_XOR16(v) __int_as_float(__builtin_amdgcn_ds_swizzle(__float_as_int(v), 0x401F))

// p-group (xor 1,2,4) full reduce
static __device__ __forceinline__ float p_reduce(float v) {
  v = dpp_add1(v);
  v = dpp_add2(v);
  v = v + SWZ_XOR4(v);
  return v;
}

// ---------------------------------------------------------------------------
// cast f (fp32, [M*C]) -> A16 (bf16, same layout). 4 elems/thread.
// ---------------------------------------------------------------------------
__global__ __launch_bounds__(256)
void cast_a_kernel(const float* __restrict__ f, __hip_bfloat16* __restrict__ A16) {
  int i = blockIdx.x * 256 + threadIdx.x;
  float4 v = ((const float4*)f)[i];
  ushort4 o;
  o.x = bf16_bits(v.x); o.y = bf16_bits(v.y);
  o.z = bf16_bits(v.z); o.w = bf16_bits(v.w);
  ((ushort4*)A16)[i] = o;
}

// ---------------------------------------------------------------------------
// Pre-transpose weights to [N][K] bf16.
// ---------------------------------------------------------------------------
__global__ __launch_bounds__(256)
void prep_w_kernel(const float* __restrict__ Wq, const float* __restrict__ Woff,
                   const float* __restrict__ Wout,
                   __hip_bfloat16* __restrict__ Wt, __hip_bfloat16* __restrict__ Wot) {
  int nrow = blockIdx.x;           // 0..895
  if (nrow < 512) {
    const float* src; int col, ld;
    if (nrow < 384) { src = Wq; col = nrow; ld = 384; }
    else            { src = Woff; col = nrow - 384; ld = 128; }
    for (int k = threadIdx.x; k < 384; k += 256)
      Wt[(size_t)nrow * 384 + k] = __float2bfloat16(src[(size_t)k * ld + col]);
  } else {
    int col = nrow - 512;
    for (int k = threadIdx.x; k < 384; k += 256)
      Wot[(size_t)col * 384 + k] = __float2bfloat16(Wout[(size_t)k * 384 + col]);
  }
}

// ---------------------------------------------------------------------------
// Transpose + cast: ft[b][n][t][c] (bf16) = f[b][t][n][c] (fp32).
// ---------------------------------------------------------------------------
__global__ __launch_bounds__(256)
void transpose_cast_kernel(const float* __restrict__ f,
                           __hip_bfloat16* __restrict__ ft) {
  const int bn = blockIdx.x;
  const int n = bn % N_;
  const int b = bn / N_;
  const size_t dst_base = (size_t)bn * (T_ * C_);
#pragma unroll
  for (int i = 0; i < 12; ++i) {
    int idx = i * 256 + threadIdx.x;
    int t = idx / C_;
    int c = idx - t * C_;
    float v = f[((size_t)(b * T_ + t) * N_ + n) * C_ + c];
    ft[dst_base + idx] = __float2bfloat16(v);
  }
}

// ---------------------------------------------------------------------------
// bf16 MFMA GEMM: out[M,N] = (A[M,384] @ Wt[N,384]^T + bias) * out0_scale.
// split=1: N=512, cols<384 -> out0 (scaled), cols>=384 -> out1 (unscaled).
// ---------------------------------------------------------------------------
__global__ __launch_bounds__(256)
void mfma_gemm_kernel(const __hip_bfloat16* __restrict__ A,
                      const __hip_bfloat16* __restrict__ Wt,
                      const float* __restrict__ b0, const float* __restrict__ b1,
                      float* __restrict__ out0, float* __restrict__ out1,
                      int split, float out0_scale) {
  __shared__ __hip_bfloat16 As[128][40];
  __shared__ __hip_bfloat16 Bs[128][40];
  const int m0 = blockIdx.x * 128;
  const int n0 = blockIdx.y * 128;
  const int tid = threadIdx.x;
  const int wv = tid >> 6, lane = tid & 63;
  const int wr = wv >> 1, wc = wv & 1;
  const int lr = lane & 15, kg = lane >> 4;

  f32x4 acc[4][4] = {};

  for (int k0 = 0; k0 < 384; k0 += 32) {
#pragma unroll
    for (int u = 0; u < 2; ++u) {
      int c = tid + u * 256;
      int row = c >> 2;
      int off = (c & 3) * 8;
      int gm = m0 + row;
      uint4 va = make_uint4(0u, 0u, 0u, 0u);
      if (gm < M_) va = *(const uint4*)(A + (size_t)gm * 384 + k0 + off);
      *(uint4*)&As[row][off] = va;
      uint4 vb = *(const uint4*)(Wt + (size_t)(n0 + row) * 384 + k0 + off);
      *(uint4*)&Bs[row][off] = vb;
    }
    __syncthreads();

    bf16x8 af[4], bfr[4];
#pragma unroll
    for (int i = 0; i < 4; ++i)
      af[i] = *(const bf16x8*)&As[wr * 64 + i * 16 + lr][kg * 8];
#pragma unroll
    for (int i = 0; i < 4; ++i)
      bfr[i] = *(const bf16x8*)&Bs[wc * 64 + i * 16 + lr][kg * 8];

#pragma unroll
    for (int mi = 0; mi < 4; ++mi)
#pragma unroll
      for (int ni = 0; ni < 4; ++ni)
        acc[mi][ni] = __builtin_amdgcn_mfma_f32_16x16x32_bf16(
            af[mi], bfr[ni], acc[mi][ni], 0, 0, 0);
    __syncthreads();
  }

  const int mrow = (lane >> 4) * 4;
#pragma unroll
  for (int mi = 0; mi < 4; ++mi) {
#pragma unroll
    for (int ni = 0; ni < 4; ++ni) {
#pragma unroll
      for (int j = 0; j < 4; ++j) {
        int gm = m0 + wr * 64 + mi * 16 + mrow + j;
        int gn = n0 + wc * 64 + ni * 16 + lr;
        if (gm >= M_) continue;
        float v = acc[mi][ni][j];
        if (!split) {
          out0[(size_t)gm * 384 + gn] = (v + b0[gn]) * out0_scale;
        } else {
          if (gn < 384) out0[(size_t)gm * 384 + gn] = (v + b0[gn]) * out0_scale;
          else          out1[(size_t)gm * 128 + (gn - 384)] = v + b1[gn - 384];
        }
      }
    }
  }
}

// ---------------------------------------------------------------------------
// Deformable attention core.
// Grid = (bn, head-quad) = 5476 blocks (XCD-chunked bijective swizzle);
// 4 waves/block, ONE head per wave, t-loop inside (L2 reuse of ft).
// Lane role: p = lane&7 (point), k = lane>>3 (channel slice d = 6k..6k+5).
//   -> softmax-over-p and oa-reduce use xor 1/2/4 (DPP + 1 swizzle, fast);
//      logit k-reduce uses xor 8/16/32 (2 swizzle + 1 bpermute).
// Tap pointers centered at r=4 so unrolled r offsets fold into imm field.
// Manual 2-wide r-pairing for shuffle-chain ILP. Q pre-scaled by
// log2e/sqrt(48) upstream -> exp2f. 1/T folded into final store.
// ---------------------------------------------------------------------------
__global__ __launch_bounds__(256, 8)
void attend_kernel(const __hip_bfloat16* __restrict__ ft,
                   const float* __restrict__ Q,
                   const float* __restrict__ OFF,
                   __hip_bfloat16* __restrict__ O1) {
  // bijective chunked XCD swizzle over grid of B*N*2 = 5476 blocks
  const int grid = B_ * N_ * 2;
  const int q8 = grid / 8, r8 = grid % 8;
  int c = blockIdx.x & 7, j = blockIdx.x >> 3;
  int id = (c < r8) ? c * (q8 + 1) + j : r8 * (q8 + 1) + (c - r8) * q8 + j;
  const int hq = id & 1;
  const int bn = id >> 1;

  const int n = bn % N_;
  const int b = bn / N_;
  const int w    = threadIdx.x >> 6;
  const int h    = hq * 4 + w;          // one head per wave
  const int lane = threadIdx.x & 63;
  const int p = lane & 7;
  const int k = lane >> 3;
  const float cy = (float)(n / HW_);
  const float cx = (float)(n % HW_);
  const int bnb = b * N_;
  const int chb = h * HD_ + 6 * k;

  for (int t = 0; t < T_; ++t) {
    const size_t row = (size_t)(b * T_ + t) * N_ + n;

    // q fragment (pre-scaled by log2e/sqrt(48) in GEMM epilogue)
    const f32x2* qp = (const f32x2*)(Q + row * C_ + h * HD_ + 6 * k);
    f32x2 q01 = qp[0], q23 = qp[1], q45 = qp[2];

    // bilinear taps for my point p
    const float* op = OFF + row * (NH_ * MP_ * 2) + h * (MP_ * 2) + p * 2;
    float y = cy + op[0];
    float x = cx + op[1];
    float y0f = floorf(y), x0f = floorf(x);
    float wy = y - y0f, wx = x - x0f;
    int y0 = (int)y0f, x0 = (int)x0f;
    int y1 = y0 + 1, x1 = x0 + 1;
    float vy0 = (y0 >= 0 && y0 < HW_) ? 1.f : 0.f;
    float vy1 = (y1 >= 0 && y1 < HW_) ? 1.f : 0.f;
    float vx0 = (x0 >= 0 && x0 < HW_) ? 1.f : 0.f;
    float vx1 = (x1 >= 0 && x1 < HW_) ? 1.f : 0.f;
    int cy0 = min(max(y0, 0), HW_ - 1), cy1 = min(max(y1, 0), HW_ - 1);
    int cx0 = min(max(x0, 0), HW_ - 1), cx1 = min(max(x1, 0), HW_ - 1);
    float tw0 = (1.f - wy) * (1.f - wx) * vy0 * vx0;
    float tw1 = (1.f - wy) * wx * vy0 * vx1;
    float tw2 = wy * (1.f - wx) * vy1 * vx0;
    float tw3 = wy * wx * vy1 * vx1;
    f32x2 tw0v = {tw0, tw0}, tw1v = {tw1, tw1}, tw2v = {tw2, tw2}, tw3v = {tw3, tw3};

    // per-tap dword pointers, centered at r=4 (imm offsets -3072..+2312 B)
    const unsigned* tp0 = (const unsigned*)(ft + ((bnb + cy0 * HW_ + cx0) * T_) * C_ + chb) + 4 * 192;
    const unsigned* tp1 = (const unsigned*)(ft + ((bnb + cy0 * HW_ + cx1) * T_) * C_ + chb) + 4 * 192;
    const unsigned* tp2 = (const unsigned*)(ft + ((bnb + cy1 * HW_ + cx0) * T_) * C_ + chb) + 4 * 192;
    const unsigned* tp3 = (const unsigned*)(ft + ((bnb + cy1 * HW_ + cx1) * T_) * C_ + chb) + 4 * 192;

    f32x2 oa01 = {0.f, 0.f}, oa23 = {0.f, 0.f}, oa45 = {0.f, 0.f};

#pragma unroll
    for (int hf = 0; hf < 4; ++hf) {
      const int rA = 2 * hf, rB = rA + 1;
      const int oA = (rA - 4) * 192, oB = (rB - 4) * 192;

      // loads for both r's of the pair
      unsigned a0A = tp0[oA + 0], a1A = tp0[oA + 1], a2A = tp0[oA + 2];
      unsigned b0A = tp1[oA + 0], b1A = tp1[oA + 1], b2A = tp1[oA + 2];
      unsigned c0A = tp2[oA + 0], c1A = tp2[oA + 1], c2A = tp2[oA + 2];
      unsigned d0A = tp3[oA + 0], d1A = tp3[oA + 1], d2A = tp3[oA + 2];
      unsigned a0B = tp0[oB + 0], a1B = tp0[oB + 1], a2B = tp0[oB + 2];
      unsigned b0B = tp1[oB + 0], b1B = tp1[oB + 1], b2B = tp1[oB + 2];
      unsigned c0B = tp2[oB + 0], c1B = tp2[oB + 1], c2B = tp2[oB + 2];
      unsigned d0B = tp3[oB + 0], d1B = tp3[oB + 1], d2B = tp3[oB + 2];

      f32x2 s01A = unpk(a0A) * tw0v + unpk(b0A) * tw1v + unpk(c0A) * tw2v + unpk(d0A) * tw3v;
      f32x2 s23A = unpk(a1A) * tw0v + unpk(b1A) * tw1v + unpk(c1A) * tw2v + unpk(d1A) * tw3v;
      f32x2 s45A = unpk(a2A) * tw0v + unpk(b2A) * tw1v + unpk(c2A) * tw2v + unpk(d2A) * tw3v;
      f32x2 s01B = unpk(a0B) * tw0v + unpk(b0B) * tw1v + unpk(c0B) * tw2v + unpk(d0B) * tw3v;
      f32x2 s23B = unpk(a1B) * tw0v + unpk(b1B) * tw1v + unpk(c1B) * tw2v + unpk(d1B) * tw3v;
      f32x2 s45B = unpk(a2B) * tw0v + unpk(b2B) * tw1v + unpk(c2B) * tw2v + unpk(d2B) * tw3v;

      f32x2 lgA2 = q01 * s01A + q23 * s23A + q45 * s45A;
      f32x2 lgB2 = q01 * s01B + q23 * s23B + q45 * s45B;
      float lgA = lgA2.x + lgA2.y;
      float lgB = lgB2.x + lgB2.y;

      // k-group reduce (xor 8,16,32), both chains interleaved
      lgA = lgA + SWZ_XOR8(lgA);
      lgB = lgB + SWZ_XOR8(lgB);
      lgA = lgA + SWZ_XOR16(lgA);
      lgB = lgB + SWZ_XOR16(lgB);
      lgA = lgA + __shfl_xor(lgA, 32);
      lgB = lgB + __shfl_xor(lgB, 32);

      // point-count masks (wave-uniform)
      int ddA = t - rA; ddA = ddA < 0 ? -ddA : ddA;
      int ddB = t - rB; ddB = ddB < 0 ? -ddB : ddB;
      int nptsA = (56 - 8 * ddA) / 7; nptsA = nptsA < 1 ? 1 : nptsA;
      int nptsB = (56 - 8 * ddB) / 7; nptsB = nptsB < 1 ? 1 : nptsB;

      // softmax over p without max-sub (logits O(1); masked -> 0)
      float eA = (p < nptsA) ? exp2f(lgA) : 0.f;
      float eB = (p < nptsB) ? exp2f(lgB) : 0.f;
      float sA = dpp_add1(eA); float sB = dpp_add1(eB);
      sA = dpp_add2(sA);       sB = dpp_add2(sB);
      sA = sA + SWZ_XOR4(sA);  sB = sB + SWZ_XOR4(sB);
      float attnA = eA * __builtin_amdgcn_rcpf(sA);
      float attnB = eB * __builtin_amdgcn_rcpf(sB);
      f32x2 avA = {attnA, attnA}, avB = {attnB, attnB};

      oa01 += avA * s01A + avB * s01B;
      oa23 += avA * s23A + avB * s23B;
      oa45 += avA * s45A + avB * s45B;
    }

    // p-reduction (xor 1,2,4 — DPP fast path), fold 1/T at store
    oa01.x = p_reduce(oa01.x); oa01.y = p_reduce(oa01.y);
    oa23.x = p_reduce(oa23.x); oa23.y = p_reduce(oa23.y);
    oa45.x = p_reduce(oa45.x); oa45.y = p_reduce(oa45.y);

    if (p == 0) {
      __hip_bfloat16* outp = O1 + row * C_ + h * HD_ + 6 * k;
      unsigned* u = (unsigned*)outp;
      u[0] = (unsigned)bf16_bits(oa01.x * 0.125f) | ((unsigned)bf16_bits(oa01.y * 0.125f) << 16);
      u[1] = (unsigned)bf16_bits(oa23.x * 0.125f) | ((unsigned)bf16_bits(oa23.y * 0.125f) << 16);
      u[2] = (unsigned)bf16_bits(oa45.x * 0.125f) | ((unsigned)bf16_bits(oa45.y * 0.125f) << 16);
    }
  }
}

// ---------------------------------------------------------------------------
extern "C" void kernel_launch(void* const* d_in, const int* in_sizes, int n_in,
                              void* d_out, int out_size, void* d_ws, size_t ws_size,
                              hipStream_t stream) {
  const float* f    = (const float*)d_in[0];
  const float* Wq   = (const float*)d_in[1];
  const float* bq   = (const float*)d_in[2];
  const float* Woff = (const float*)d_in[3];
  const float* boff = (const float*)d_in[4];
  const float* Wout = (const float*)d_in[5];
  const float* bout = (const float*)d_in[6];
  float* outp = (float*)d_out;

  float* Qbuf = (float*)d_ws;
  float* OFFb = Qbuf + (size_t)M_ * C_;
  __hip_bfloat16* ft  = (__hip_bfloat16*)(OFFb + (size_t)M_ * 128);
  __hip_bfloat16* A16 = ft + (size_t)B_ * N_ * T_ * C_;
  __hip_bfloat16* O1  = A16;   // alias: A16 dead after GEMM1, O1 written by attend
  __hip_bfloat16* Wt  = A16 + (size_t)M_ * C_;
  __hip_bfloat16* Wot = Wt + (size_t)512 * 384;

  dim3 blk(256);

  cast_a_kernel<<<dim3((M_ * C_) / 4 / 256), blk, 0, stream>>>(f, A16);
  prep_w_kernel<<<dim3(896), blk, 0, stream>>>(Wq, Woff, Wout, Wt, Wot);
  transpose_cast_kernel<<<dim3(B_ * N_), blk, 0, stream>>>(f, ft);

  // fused q+off GEMM: [M,384] @ [384,512] -> Qbuf (x log2e/sqrt(48)) / OFFb
  mfma_gemm_kernel<<<dim3((M_ + 127) / 128, 4), blk, 0, stream>>>(
      A16, Wt, bq, boff, Qbuf, OFFb, 1, 0.20822825268806912f);

  attend_kernel<<<dim3(B_ * N_ * 2), blk, 0, stream>>>(ft, Qbuf, OFFb, O1);

  // output GEMM: [M,384] @ [384,384] -> outp
  mfma_gemm_kernel<<<dim3((M_ + 127) / 128, 3), blk, 0, stream>>>(
      O1, Wot, bout, nullptr, outp, nullptr, 0, 1.0f);
}

// Round 7
// 312.654 us; speedup vs baseline: 2.4184x; 2.4184x over previous
//
#include <hip/hip_runtime.h>
#include <hip/hip_bf16.h>
#include <cstddef>

// Problem constants
constexpr int B_  = 2;
constexpr int T_  = 8;
constexpr int HW_ = 37;          // H == W == 37
constexpr int N_  = HW_ * HW_;   // 1369
constexpr int C_  = 384;
constexpr int NH_ = 8;
constexpr int MP_ = 8;
constexpr int HD_ = C_ / NH_;    // 48
constexpr int M_  = B_ * T_ * N_; // 21904

typedef short bf16x8 __attribute__((ext_vector_type(8)));
typedef float f32x4 __attribute__((ext_vector_type(4)));
typedef float f32x2 __attribute__((ext_vector_type(2)));

static __device__ __forceinline__ unsigned short bf16_bits(float v) {
  __hip_bfloat16 b = __float2bfloat16(v);
  return *reinterpret_cast<unsigned short*>(&b);
}

static __device__ __forceinline__ f32x2 unpk(unsigned u) {
  f32x2 r;
  r.x = __uint_as_float(u << 16);
  r.y = __uint_as_float(u & 0xffff0000u);
  return r;
}

// ---------------------------------------------------------------------------
// Fused cast + transpose. One pass over f (fp32 [B,T,N,C]):
//   A16[b][t][n][c] = bf16(f)          (same layout, feeds GEMM1)
//   ft [b][n][t][c] = bf16(f)          (T adjacent to C, feeds attend)
// ---------------------------------------------------------------------------
__global__ __launch_bounds__(256)
void cast_transpose_kernel(const float* __restrict__ f,
                           __hip_bfloat16* __restrict__ A16,
                           __hip_bfloat16* __restrict__ ft) {
  const int bn = blockIdx.x;          // b*N + n
  const int n = bn % N_;
  const int b = bn / N_;
  const size_t dst_base = (size_t)bn * (T_ * C_);
#pragma unroll
  for (int i = 0; i < 12; ++i) {      // 12*256 = 3072 = T*C
    int idx = i * 256 + threadIdx.x;  // t*C + c
    int t = idx / C_;
    int c = idx - t * C_;
    size_t src = ((size_t)(b * T_ + t) * N_ + n) * C_ + c;
    __hip_bfloat16 v = __float2bfloat16(f[src]);
    ft[dst_base + idx] = v;
    A16[src] = v;
  }
}

// ---------------------------------------------------------------------------
// Pre-transpose weights to [N][K] bf16.
// ---------------------------------------------------------------------------
__global__ __launch_bounds__(256)
void prep_w_kernel(const float* __restrict__ Wq, const float* __restrict__ Woff,
                   const float* __restrict__ Wout,
                   __hip_bfloat16* __restrict__ Wt, __hip_bfloat16* __restrict__ Wot) {
  int nrow = blockIdx.x;           // 0..895
  if (nrow < 512) {
    const float* src; int col, ld;
    if (nrow < 384) { src = Wq; col = nrow; ld = 384; }
    else            { src = Woff; col = nrow - 384; ld = 128; }
    for (int k = threadIdx.x; k < 384; k += 256)
      Wt[(size_t)nrow * 384 + k] = __float2bfloat16(src[(size_t)k * ld + col]);
  } else {
    int col = nrow - 512;
    for (int k = threadIdx.x; k < 384; k += 256)
      Wot[(size_t)col * 384 + k] = __float2bfloat16(Wout[(size_t)k * 384 + col]);
  }
}

// ---------------------------------------------------------------------------
// bf16 MFMA GEMM: out[M,N] = (A[M,384] @ Wt[N,384]^T + bias) * out0_scale.
// split=1: N=512, cols<384 -> out0 (scaled), cols>=384 -> out1 (unscaled).
// ---------------------------------------------------------------------------
__global__ __launch_bounds__(256)
void mfma_gemm_kernel(const __hip_bfloat16* __restrict__ A,
                      const __hip_bfloat16* __restrict__ Wt,
                      const float* __restrict__ b0, const float* __restrict__ b1,
                      float* __restrict__ out0, float* __restrict__ out1,
                      int split, float out0_scale) {
  __shared__ __hip_bfloat16 As[128][40];
  __shared__ __hip_bfloat16 Bs[128][40];
  const int m0 = blockIdx.x * 128;
  const int n0 = blockIdx.y * 128;
  const int tid = threadIdx.x;
  const int wv = tid >> 6, lane = tid & 63;
  const int wr = wv >> 1, wc = wv & 1;
  const int lr = lane & 15, kg = lane >> 4;

  f32x4 acc[4][4] = {};

  for (int k0 = 0; k0 < 384; k0 += 32) {
#pragma unroll
    for (int u = 0; u < 2; ++u) {
      int c = tid + u * 256;
      int row = c >> 2;
      int off = (c & 3) * 8;
      int gm = m0 + row;
      uint4 va = make_uint4(0u, 0u, 0u, 0u);
      if (gm < M_) va = *(const uint4*)(A + (size_t)gm * 384 + k0 + off);
      *(uint4*)&As[row][off] = va;
      uint4 vb = *(const uint4*)(Wt + (size_t)(n0 + row) * 384 + k0 + off);
      *(uint4*)&Bs[row][off] = vb;
    }
    __syncthreads();

    bf16x8 af[4], bfr[4];
#pragma unroll
    for (int i = 0; i < 4; ++i)
      af[i] = *(const bf16x8*)&As[wr * 64 + i * 16 + lr][kg * 8];
#pragma unroll
    for (int i = 0; i < 4; ++i)
      bfr[i] = *(const bf16x8*)&Bs[wc * 64 + i * 16 + lr][kg * 8];

#pragma unroll
    for (int mi = 0; mi < 4; ++mi)
#pragma unroll
      for (int ni = 0; ni < 4; ++ni)
        acc[mi][ni] = __builtin_amdgcn_mfma_f32_16x16x32_bf16(
            af[mi], bfr[ni], acc[mi][ni], 0, 0, 0);
    __syncthreads();
  }

  const int mrow = (lane >> 4) * 4;
#pragma unroll
  for (int mi = 0; mi < 4; ++mi) {
#pragma unroll
    for (int ni = 0; ni < 4; ++ni) {
#pragma unroll
      for (int j = 0; j < 4; ++j) {
        int gm = m0 + wr * 64 + mi * 16 + mrow + j;
        int gn = n0 + wc * 64 + ni * 16 + lr;
        if (gm >= M_) continue;
        float v = acc[mi][ni][j];
        if (!split) {
          out0[(size_t)gm * 384 + gn] = (v + b0[gn]) * out0_scale;
        } else {
          if (gn < 384) out0[(size_t)gm * 384 + gn] = (v + b0[gn]) * out0_scale;
          else          out1[(size_t)gm * 128 + (gn - 384)] = v + b1[gn - 384];
        }
      }
    }
  }
}

// ---------------------------------------------------------------------------
// Deformable attention core (round-5 version — known-good, no spills).
// Grid = (bn, head-quad) = 5476 blocks (XCD-chunked bijective swizzle);
// 4 waves/block, ONE head per wave, t-loop inside (L2 reuse of ft).
// Lane role: p = lane>>3 (point), k = lane&7 (channel slice d = 6k..6k+5).
// Softmax without max-sub (logits O(1), masked -> e=0). Packed f32x2 math.
// log2e/sqrt(48) folded into Q upstream; 1/T folded into final store.
// ---------------------------------------------------------------------------
__global__ __launch_bounds__(256)
void attend_kernel(const __hip_bfloat16* __restrict__ ft,
                   const float* __restrict__ Q,
                   const float* __restrict__ OFF,
                   __hip_bfloat16* __restrict__ O1) {
  // bijective chunked XCD swizzle over grid of B*N*2 = 5476 blocks
  const int grid = B_ * N_ * 2;
  const int q8 = grid / 8, r8 = grid % 8;
  int c = blockIdx.x & 7, j = blockIdx.x >> 3;
  int id = (c < r8) ? c * (q8 + 1) + j : r8 * (q8 + 1) + (c - r8) * q8 + j;
  const int hq = id & 1;
  const int bn = id >> 1;

  const int n = bn % N_;
  const int b = bn / N_;
  const int w    = threadIdx.x >> 6;
  const int h    = hq * 4 + w;          // one head per wave
  const int lane = threadIdx.x & 63;
  const int p = lane >> 3;
  const int k = lane & 7;
  const float cy = (float)(n / HW_);
  const float cx = (float)(n % HW_);
  const int bnb = b * N_;
  const int chb = h * HD_ + 6 * k;

  for (int t = 0; t < T_; ++t) {
    const size_t row = (size_t)(b * T_ + t) * N_ + n;

    // q fragment (pre-scaled by log2e/sqrt(48) in GEMM epilogue)
    const f32x2* qp = (const f32x2*)(Q + row * C_ + h * HD_ + 6 * k);
    f32x2 q01 = qp[0], q23 = qp[1], q45 = qp[2];

    // bilinear taps for my point p
    const float* op = OFF + row * (NH_ * MP_ * 2) + h * (MP_ * 2) + p * 2;
    float y = cy + op[0];
    float x = cx + op[1];
    float y0f = floorf(y), x0f = floorf(x);
    float wy = y - y0f, wx = x - x0f;
    int y0 = (int)y0f, x0 = (int)x0f;
    int y1 = y0 + 1, x1 = x0 + 1;
    float vy0 = (y0 >= 0 && y0 < HW_) ? 1.f : 0.f;
    float vy1 = (y1 >= 0 && y1 < HW_) ? 1.f : 0.f;
    float vx0 = (x0 >= 0 && x0 < HW_) ? 1.f : 0.f;
    float vx1 = (x1 >= 0 && x1 < HW_) ? 1.f : 0.f;
    int cy0 = min(max(y0, 0), HW_ - 1), cy1 = min(max(y1, 0), HW_ - 1);
    int cx0 = min(max(x0, 0), HW_ - 1), cx1 = min(max(x1, 0), HW_ - 1);
    float tw0 = (1.f - wy) * (1.f - wx) * vy0 * vx0;
    float tw1 = (1.f - wy) * wx * vy0 * vx1;
    float tw2 = wy * (1.f - wx) * vy1 * vx0;
    float tw3 = wy * wx * vy1 * vx1;
    f32x2 tw0v = {tw0, tw0}, tw1v = {tw1, tw1}, tw2v = {tw2, tw2}, tw3v = {tw3, tw3};

    int base0 = ((bnb + cy0 * HW_ + cx0) * T_) * C_ + chb;
    int base1 = ((bnb + cy0 * HW_ + cx1) * T_) * C_ + chb;
    int base2 = ((bnb + cy1 * HW_ + cx0) * T_) * C_ + chb;
    int base3 = ((bnb + cy1 * HW_ + cx1) * T_) * C_ + chb;

    f32x2 oa01 = {0.f, 0.f}, oa23 = {0.f, 0.f}, oa45 = {0.f, 0.f};

#pragma unroll
    for (int r = 0; r < T_; ++r) {
      const int roff = r * C_;
      const unsigned* ta = (const unsigned*)(ft + base0 + roff);
      const unsigned* tb = (const unsigned*)(ft + base1 + roff);
      const unsigned* tc = (const unsigned*)(ft + base2 + roff);
      const unsigned* td = (const unsigned*)(ft + base3 + roff);
      unsigned ua0 = ta[0], ua1 = ta[1], ua2 = ta[2];
      unsigned ub0 = tb[0], ub1 = tb[1], ub2 = tb[2];
      unsigned uc0 = tc[0], uc1 = tc[1], uc2 = tc[2];
      unsigned ud0 = td[0], ud1 = td[1], ud2 = td[2];

      f32x2 s01 = unpk(ua0) * tw0v + unpk(ub0) * tw1v + unpk(uc0) * tw2v + unpk(ud0) * tw3v;
      f32x2 s23 = unpk(ua1) * tw0v + unpk(ub1) * tw1v + unpk(uc1) * tw2v + unpk(ud1) * tw3v;
      f32x2 s45 = unpk(ua2) * tw0v + unpk(ub2) * tw1v + unpk(uc2) * tw2v + unpk(ud2) * tw3v;

      // logit: packed dot + horizontal add, then k-group reduce (xor 1,2,4)
      f32x2 lg2 = q01 * s01 + q23 * s23 + q45 * s45;
      float lg = lg2.x + lg2.y;
      lg += __shfl_xor(lg, 1);
      lg += __shfl_xor(lg, 2);
      lg += __shfl_xor(lg, 4);

      // point-count mask for this (t, r)
      int dd = t - r; dd = dd < 0 ? -dd : dd;
      int npts = (56 - 8 * dd) / 7; npts = npts < 1 ? 1 : npts;

      // softmax over p without max-sub (logits O(1); masked -> 0)
      float e = (p < npts) ? exp2f(lg) : 0.f;
      float ssum = e;
      ssum += __shfl_xor(ssum, 8);
      ssum += __shfl_xor(ssum, 16);
      ssum += __shfl_xor(ssum, 32);
      float attn = e * __builtin_amdgcn_rcpf(ssum);
      f32x2 attnv = {attn, attn};

      oa01 += attnv * s01;
      oa23 += attnv * s23;
      oa45 += attnv * s45;
    }

    // p-reduction (once per (t,h)), fold 1/T
    oa01.x += __shfl_xor(oa01.x, 8); oa01.x += __shfl_xor(oa01.x, 16); oa01.x += __shfl_xor(oa01.x, 32);
    oa01.y += __shfl_xor(oa01.y, 8); oa01.y += __shfl_xor(oa01.y, 16); oa01.y += __shfl_xor(oa01.y, 32);
    oa23.x += __shfl_xor(oa23.x, 8); oa23.x += __shfl_xor(oa23.x, 16); oa23.x += __shfl_xor(oa23.x, 32);
    oa23.y += __shfl_xor(oa23.y, 8); oa23.y += __shfl_xor(oa23.y, 16); oa23.y += __shfl_xor(oa23.y, 32);
    oa45.x += __shfl_xor(oa45.x, 8); oa45.x += __shfl_xor(oa45.x, 16); oa45.x += __shfl_xor(oa45.x, 32);
    oa45.y += __shfl_xor(oa45.y, 8); oa45.y += __shfl_xor(oa45.y, 16); oa45.y += __shfl_xor(oa45.y, 32);

    if (p == 0) {
      __hip_bfloat16* outp = O1 + row * C_ + h * HD_ + 6 * k;
      unsigned* u = (unsigned*)outp;
      u[0] = (unsigned)bf16_bits(oa01.x * 0.125f) | ((unsigned)bf16_bits(oa01.y * 0.125f) << 16);
      u[1] = (unsigned)bf16_bits(oa23.x * 0.125f) | ((unsigned)bf16_bits(oa23.y * 0.125f) << 16);
      u[2] = (unsigned)bf16_bits(oa45.x * 0.125f) | ((unsigned)bf16_bits(oa45.y * 0.125f) << 16);
    }
  }
}

// ---------------------------------------------------------------------------
extern "C" void kernel_launch(void* const* d_in, const int* in_sizes, int n_in,
                              void* d_out, int out_size, void* d_ws, size_t ws_size,
                              hipStream_t stream) {
  const float* f    = (const float*)d_in[0];
  const float* Wq   = (const float*)d_in[1];
  const float* bq   = (const float*)d_in[2];
  const float* Woff = (const float*)d_in[3];
  const float* boff = (const float*)d_in[4];
  const float* Wout = (const float*)d_in[5];
  const float* bout = (const float*)d_in[6];
  float* outp = (float*)d_out;

  float* Qbuf = (float*)d_ws;
  float* OFFb = Qbuf + (size_t)M_ * C_;
  __hip_bfloat16* ft  = (__hip_bfloat16*)(OFFb + (size_t)M_ * 128);
  __hip_bfloat16* A16 = ft + (size_t)B_ * N_ * T_ * C_;
  __hip_bfloat16* O1  = A16;   // alias: A16 dead after GEMM1, O1 written by attend
  __hip_bfloat16* Wt  = A16 + (size_t)M_ * C_;
  __hip_bfloat16* Wot = Wt + (size_t)512 * 384;

  dim3 blk(256);

  cast_transpose_kernel<<<dim3(B_ * N_), blk, 0, stream>>>(f, A16, ft);
  prep_w_kernel<<<dim3(896), blk, 0, stream>>>(Wq, Woff, Wout, Wt, Wot);

  // fused q+off GEMM: [M,384] @ [384,512] -> Qbuf (x log2e/sqrt(48)) / OFFb
  mfma_gemm_kernel<<<dim3((M_ + 127) / 128, 4), blk, 0, stream>>>(
      A16, Wt, bq, boff, Qbuf, OFFb, 1, 0.20822825268806912f);

  attend_kernel<<<dim3(B_ * N_ * 2), blk, 0, stream>>>(ft, Qbuf, OFFb, O1);

  // output GEMM: [M,384] @ [384,384] -> outp
  mfma_gemm_kernel<<<dim3((M_ + 127) / 128, 3), blk, 0, stream>>>(
      O1, Wot, bout, nullptr, outp, nullptr, 0, 1.0f);
}